// Round 1
// baseline (369.087 us; speedup 1.0000x reference)
//
#include <hip/hip_runtime.h>
#include <hip/hip_bf16.h>
#include <stdint.h>

// Problem constants
#define NN 8192
#define CC 16
#define RPB 64              // rows per block (4 waves x 16 rows)
#define COLSPLIT 16         // column splits -> grid = 128 * 16 = 2048 blocks
#define CPB (NN / COLSPLIT) // 512 columns per block
#define NCHUNK (NN / 32)    // 256 K-chunks of 32 columns
#define ITERS (CPB / 32)    // 16 K-iterations per block

typedef __attribute__((ext_vector_type(8))) short bf16x8;
typedef __attribute__((ext_vector_type(4))) float f32x4;
typedef __attribute__((ext_vector_type(4))) unsigned int u32x4;

// ws layout:
//   +0     double quad_acc
//   +64    int    cnt_acc
//   +256   double dH[16], stride 256 B (avoid same-line atomic serialization)
//   +8192  B-fragment table: [2 pass][256 chunk][64 lane] x 16 B = 512 KB

__device__ __forceinline__ unsigned short f32_to_bf16(float f) {
  unsigned int u = __float_as_uint(f);
  u = u + 0x7FFFu + ((u >> 16) & 1u);  // RNE
  return (unsigned short)(u >> 16);
}
__device__ __forceinline__ float bf16_to_f32(unsigned short h) {
  return __uint_as_float(((unsigned int)h) << 16);
}

__global__ void initk(double* quad, int* cnt, double* dHa) {
  int t = threadIdx.x;
  if (t < CC) dHa[t * 32] = 0.0;
  if (t == 16) *quad = 0.0;
  if (t == 17) *cnt = 0;
}

// Pre-pack H (hi/lo bf16 split) into MFMA B-fragment order:
// B[k][n]: n = lane&15, k = (lane>>4)*8 + idx  (16x16x32 bf16)
__global__ void prep_btab(const float* __restrict__ H, u32x4* __restrict__ btab) {
  int t = blockIdx.x * blockDim.x + threadIdx.x;  // 0 .. 2*256*64-1
  int lane = t & 63;
  int chunk = (t >> 6) & (NCHUNK - 1);
  int pass = t >> 14;  // 0 = hi, 1 = lo
  int c = lane & 15, q = lane >> 4;
  int j0 = chunk * 32 + q * 8;
  unsigned int w[4];
#pragma unroll
  for (int p = 0; p < 4; ++p) {
    unsigned int r = 0;
#pragma unroll
    for (int e = 0; e < 2; ++e) {
      float x = H[(size_t)(j0 + 2 * p + e) * CC + c];
      unsigned short hb = f32_to_bf16(x);
      unsigned short bits = hb;
      if (pass) bits = f32_to_bf16(x - bf16_to_f32(hb));
      r |= ((unsigned int)bits) << (16 * e);
    }
    w[p] = r;
  }
  u32x4 o; o.x = w[0]; o.y = w[1]; o.z = w[2]; o.w = w[3];
  btab[t] = o;
}

template <int USE_BT>
__global__ __launch_bounds__(256, 4) void main_k(
    const float* __restrict__ A, const float* __restrict__ H,
    const u32x4* __restrict__ btab,
    double* __restrict__ quad_acc, double* __restrict__ dHa,
    int* __restrict__ cnt_acc) {
  __shared__ float sdH[4][16];
  __shared__ float squad[4];
  __shared__ int scnt[4];

  int tid = threadIdx.x;
  int wave = tid >> 6, lane = tid & 63;
  int rb = blockIdx.x / COLSPLIT, cb = blockIdx.x % COLSPLIT;
  int m = lane & 15, q = lane >> 4;
  int row0 = rb * RPB + wave * 16;
  int col0 = cb * CPB;

  // A fragment source: A[row0+m][col0 + q*8 + ...], 2x float4 per chunk
  const float* arow = A + (size_t)(row0 + m) * NN + col0 + q * 8;
  const u32x4* bth = nullptr; const u32x4* btl = nullptr;
  if (USE_BT) {
    int chunk0 = col0 >> 5;
    bth = btab + (size_t)chunk0 * 64 + lane;
    btl = bth + (size_t)NCHUNK * 64;
  }

  f32x4 acc_h = {0.f, 0.f, 0.f, 0.f};
  f32x4 acc_l = {0.f, 0.f, 0.f, 0.f};
  int cnt = 0;

#pragma unroll 2
  for (int it = 0; it < ITERS; ++it) {
    f32x4 a0 = *(const f32x4*)(arow + it * 32);
    f32x4 a1 = *(const f32x4*)(arow + it * 32 + 4);
    u32x4 bh, bl;
    if (USE_BT) {
      bh = bth[it * 64];
      bl = btl[it * 64];
    } else {
      // fallback: gather H and split on the fly
      const float* hp = H + (size_t)(col0 + it * 32 + q * 8) * CC + m;
      unsigned int wh[4], wl[4];
#pragma unroll
      for (int p = 0; p < 4; ++p) {
        float x0 = hp[(2 * p) * CC], x1 = hp[(2 * p + 1) * CC];
        unsigned short h0 = f32_to_bf16(x0), h1 = f32_to_bf16(x1);
        unsigned short l0 = f32_to_bf16(x0 - bf16_to_f32(h0));
        unsigned short l1 = f32_to_bf16(x1 - bf16_to_f32(h1));
        wh[p] = (unsigned int)h0 | ((unsigned int)h1 << 16);
        wl[p] = (unsigned int)l0 | ((unsigned int)l1 << 16);
      }
      bh.x = wh[0]; bh.y = wh[1]; bh.z = wh[2]; bh.w = wh[3];
      bl.x = wl[0]; bl.y = wl[1]; bl.z = wl[2]; bl.w = wl[3];
    }
    // threshold A>0 -> packed bf16 {1.0, 0.0}, A-frag layout k = q*8+idx
    unsigned int p0 = (a0.x > 0.f ? 0x3F80u : 0u) | (a0.y > 0.f ? 0x3F800000u : 0u);
    unsigned int p1 = (a0.z > 0.f ? 0x3F80u : 0u) | (a0.w > 0.f ? 0x3F800000u : 0u);
    unsigned int p2 = (a1.x > 0.f ? 0x3F80u : 0u) | (a1.y > 0.f ? 0x3F800000u : 0u);
    unsigned int p3 = (a1.z > 0.f ? 0x3F80u : 0u) | (a1.w > 0.f ? 0x3F800000u : 0u);
    cnt += __popc(p0 & 0x00800080u) + __popc(p1 & 0x00800080u) +
           __popc(p2 & 0x00800080u) + __popc(p3 & 0x00800080u);
    u32x4 af; af.x = p0; af.y = p1; af.z = p2; af.w = p3;
    bf16x8 afrag = __builtin_bit_cast(bf16x8, af);
    acc_h = __builtin_amdgcn_mfma_f32_16x16x32_bf16(afrag, __builtin_bit_cast(bf16x8, bh), acc_h, 0, 0, 0);
    acc_l = __builtin_amdgcn_mfma_f32_16x16x32_bf16(afrag, __builtin_bit_cast(bf16x8, bl), acc_l, 0, 0, 0);
  }

  // C/D layout (16x16): col c = lane&15, row = q*4 + reg
  f32x4 af = acc_h + acc_l;  // r_i[c] partial (this wave's column stripe)

  // dH partial: sum r over this wave's 16 rows, per class c = lane&15
  float rowsum = af.x + af.y + af.z + af.w;
  rowsum += __shfl_xor(rowsum, 16, 64);
  rowsum += __shfl_xor(rowsum, 32, 64);

  // quad partial: sum_i H[i][c] * r_i[c]
  const float* hr = H + (size_t)(row0 + q * 4) * CC + m;
  float qp = af.x * hr[0] + af.y * hr[CC] + af.z * hr[2 * CC] + af.w * hr[3 * CC];
#pragma unroll
  for (int d = 1; d < 64; d <<= 1) qp += __shfl_xor(qp, d, 64);
#pragma unroll
  for (int d = 1; d < 64; d <<= 1) cnt += __shfl_xor(cnt, d, 64);

  if (lane < 16) sdH[wave][lane] = rowsum;
  if (lane == 0) { squad[wave] = qp; scnt[wave] = cnt; }
  __syncthreads();
  if (tid < 16) {
    atomicAdd(&dHa[tid * 32],
              (double)(sdH[0][tid] + sdH[1][tid] + sdH[2][tid] + sdH[3][tid]));
  } else if (tid == 16) {
    atomicAdd(quad_acc, (double)(squad[0] + squad[1] + squad[2] + squad[3]));
  } else if (tid == 17) {
    atomicAdd(cnt_acc, scnt[0] + scnt[1] + scnt[2] + scnt[3]);
  }
}

__global__ void finalize(const double* quad, const int* cnt, const double* dHa,
                         float* out) {
  if (threadIdx.x == 0) {
    double s = (double)(*cnt);
    double d2 = 0.0;
#pragma unroll
    for (int c = 0; c < CC; ++c) { double v = dHa[c * 32]; d2 += v * v; }
    out[0] = (float)(((*quad) - d2 / s) / s);
  }
}

extern "C" void kernel_launch(void* const* d_in, const int* in_sizes, int n_in,
                              void* d_out, int out_size, void* d_ws, size_t ws_size,
                              hipStream_t stream) {
  const float* H = (const float*)d_in[0];
  const float* A = (const float*)d_in[1];
  if (n_in >= 2 && in_sizes[0] != NN * CC) {  // defensive: input order
    H = (const float*)d_in[1];
    A = (const float*)d_in[0];
  }
  float* out = (float*)d_out;
  char* ws = (char*)d_ws;
  double* quad = (double*)(ws + 0);
  int* cnt = (int*)(ws + 64);
  double* dHa = (double*)(ws + 256);
  u32x4* btab = (u32x4*)(ws + 8192);
  const size_t need = 8192 + (size_t)2 * NCHUNK * 64 * 16;
  bool use_bt = ws_size >= need;

  initk<<<1, 32, 0, stream>>>(quad, cnt, dHa);
  if (use_bt) {
    prep_btab<<<(2 * NCHUNK * 64) / 256, 256, 0, stream>>>(H, btab);
    main_k<1><<<(NN / RPB) * COLSPLIT, 256, 0, stream>>>(A, H, btab, quad, dHa, cnt);
  } else {
    main_k<0><<<(NN / RPB) * COLSPLIT, 256, 0, stream>>>(A, H, nullptr, quad, dHa, cnt);
  }
  finalize<<<1, 64, 0, stream>>>(quad, cnt, dHa, out);
}